// Round 17
// baseline (262.258 us; speedup 1.0000x reference)
//
#include <hip/hip_runtime.h>
#include <hip/hip_bf16.h>

#define EPS 1e-5f
#define SLOPE 0.2f

#define NF 16      // frames = T-1
#define NBATCH 16  // batch B
#define NC 512     // channels C (= GEMM N and K)
#define NHW 256    // H*W
#define ND 256     // cond dim D
#define K2 768     // C + D (conv2_w row stride)
#define MF 4096    // per-frame GEMM M = B*HW
#define FRAME_ELEMS ((size_t)MF * NC)   // 2,097,152

typedef __attribute__((ext_vector_type(8))) short short8;
typedef __attribute__((ext_vector_type(4))) float float4v;
typedef __attribute__((ext_vector_type(16))) float float16v;

__device__ __forceinline__ float lrelu(float v) { return v >= 0.f ? v : SLOPE * v; }
__device__ __forceinline__ float b2f(ushort u) { union { float f; uint i; } x; x.i = ((uint)u) << 16; return x.f; }
__device__ __forceinline__ ushort f2b(float f) {
  uint i = __float_as_uint(f);
  return (ushort)((i + 0x7FFFu + ((i >> 16) & 1u)) >> 16);
}
__device__ __forceinline__ void gl16(const void* g, void* l) {
  __builtin_amdgcn_global_load_lds(
      (const __attribute__((address_space(1))) unsigned int*)g,
      (__attribute__((address_space(3))) unsigned int*)l, 16, 0, 0);
}
#define SB __builtin_amdgcn_sched_barrier(0)

// ---------------- fused prep: weights->bf16 + sent(LDS) + bias2 -----------------
__global__ __launch_bounds__(256) void k_pre(
    const float* __restrict__ w1, const float* __restrict__ w2,
    const float* __restrict__ cond, const float* __restrict__ lin_w,
    const float* __restrict__ lin_b, const float* __restrict__ gam,
    const float* __restrict__ bet,
    ushort* __restrict__ w1b, ushort* __restrict__ w2b,
    float* __restrict__ bias2) {
  int bx = blockIdx.x, t = threadIdx.x;
  if (bx < 1024) {
    int i = bx * 256 + t;
    w1b[i] = f2b(w1[i]);
    int o = i >> 9, c = i & 511;
    w2b[i] = f2b(w2[(size_t)o * K2 + c]);
    return;
  }
  __shared__ float sl[NBATCH][ND];
  int d = t;
  {
    float acc[NBATCH];
    float bias = lin_b[d];
#pragma unroll
    for (int b = 0; b < NBATCH; ++b) acc[b] = bias;
    for (int k = 0; k < ND; ++k) {
      float w = lin_w[d * ND + k];
#pragma unroll
      for (int b = 0; b < NBATCH; ++b) acc[b] = fmaf(cond[b * ND + k], w, acc[b]);
    }
    float mu = 0.f;
#pragma unroll
    for (int b = 0; b < NBATCH; ++b) mu += acc[b];
    mu *= (1.f / NBATCH);
    float var = 0.f;
#pragma unroll
    for (int b = 0; b < NBATCH; ++b) { float x = acc[b] - mu; var = fmaf(x, x, var); }
    var *= (1.f / NBATCH);
    float sc = rsqrtf(var + EPS) * gam[d];
    float sh = bet[d] - mu * sc;
#pragma unroll
    for (int b = 0; b < NBATCH; ++b) sl[b][d] = lrelu(fmaf(acc[b], sc, sh));
  }
  __syncthreads();
  int o = (bx - 1024) * 256 + t;
  float acc2[NBATCH];
#pragma unroll
  for (int b = 0; b < NBATCH; ++b) acc2[b] = 0.f;
  for (int d2 = 0; d2 < ND; ++d2) {
    float wv = w2[(size_t)o * K2 + NC + d2];
#pragma unroll
    for (int b = 0; b < NBATCH; ++b) acc2[b] = fmaf(sl[b][d2], wv, acc2[b]);
  }
#pragma unroll
  for (int b = 0; b < NBATCH; ++b) bias2[b * NC + o] = acc2[b];
}

// ---------------- motions v5: micro-transpose + frame-group-4 register carry -----
__global__ __launch_bounds__(256) void k_mot(
    const float* __restrict__ xbar, ushort* __restrict__ mot, int f0, int nb) {
  __shared__ ushort T2[64][72];
  int t = threadIdx.x;
  int b = blockIdx.y;
  int hw0 = (blockIdx.x & 3) * 64;
  int c0 = (blockIdx.x >> 2) * 64;
  int fg = blockIdx.z * 4;
  int fe = fg + 4 < nb ? fg + 4 : nb;

  int c4 = t >> 4;
  int h16 = t & 15;
  const size_t fstride = (size_t)NBATCH * NC * NHW;
  const float* base = xbar + ((size_t)(f0 + fg) * NBATCH + b) * (NC * NHW) +
                      (size_t)(c0 + c4 * 4) * NHW + hw0 + h16 * 4;

  float4 prev[4], cur[4], nxt[4];
#pragma unroll
  for (int r = 0; r < 4; ++r) prev[r] = *(const float4*)(base + (size_t)r * NHW);
#pragma unroll
  for (int r = 0; r < 4; ++r) cur[r] = *(const float4*)(base + fstride + (size_t)r * NHW);

  for (int fr = fg; fr < fe; ++fr) {
    if (fr + 1 < fe) {
      const float* xn = base + (size_t)(fr - fg + 2) * fstride;
#pragma unroll
      for (int r = 0; r < 4; ++r) nxt[r] = *(const float4*)(xn + (size_t)r * NHW);
    }
#pragma unroll
    for (int i = 0; i < 4; ++i) {
      ushort4 pk = make_ushort4(
          f2b(((const float*)&cur[0])[i] - ((const float*)&prev[0])[i]),
          f2b(((const float*)&cur[1])[i] - ((const float*)&prev[1])[i]),
          f2b(((const float*)&cur[2])[i] - ((const float*)&prev[2])[i]),
          f2b(((const float*)&cur[3])[i] - ((const float*)&prev[3])[i]));
      *(ushort4*)&T2[h16 * 4 + i][c4 * 4] = pk;
    }
    __syncthreads();
    ushort* mp = mot + ((size_t)fr * MF + b * NHW + hw0) * NC + c0;
#pragma unroll
    for (int it = 0; it < 2; ++it) {
      int unit = it * 256 + t;
      int hw = unit >> 3, q = unit & 7;
      short8 v = *(const short8*)&T2[hw][q * 8];
      *(short8*)&mp[(size_t)hw * NC + q * 8] = v;
    }
    __syncthreads();
#pragma unroll
    for (int r = 0; r < 4; ++r) { prev[r] = cur[r]; cur[r] = nxt[r]; }
  }
}

// ---------------- 256x256 8-wave MFMA GEMM, 32x32x16 core, counted-vmcnt dbuf ----
// Wave tile 128m x 64n = 4x2 tiles of 32x32; acc = 8 x float16v (128 regs).
// K-tile BK=64 = 4 ksteps of K=16, split into 2 phases (ks 0-1, ks 2-3).
template <int BIAS>
__global__ __launch_bounds__(512, 1) void k_gemm8(
    const ushort* __restrict__ A, const ushort* __restrict__ W,
    const float* __restrict__ bias2, ushort* __restrict__ H,
    float2* __restrict__ part) {
  __shared__ ushort lds[65536];  // [buf][A:16384|B:16384]
  const int t = threadIdx.x, w = t >> 6, l = t & 63;
  const int g = blockIdx.z, bx = blockIdx.x, ny = blockIdx.y;
  const int m0 = bx * 256, n0 = ny * 256;
  const int wr = w >> 2, wc = w & 3;

  const ushort* Ag = A + (size_t)g * FRAME_ELEMS + (size_t)m0 * NC;
  const ushort* Wg = W + (size_t)n0 * NC;

  size_t goff[4];
  int loff[4];
#pragma unroll
  for (int q = 0; q < 4; ++q) {
    int u = w * 256 + q * 64 + l;
    int row = u >> 3, cb = (u & 7) ^ (row & 7);
    goff[q] = (size_t)row * NC + cb * 8;
    loff[q] = u * 8;
  }

#define STAGE8(t_, b_)                                               \
  do {                                                               \
    const int k0_ = (t_) * 64;                                       \
    _Pragma("unroll") for (int q = 0; q < 4; ++q)                    \
        gl16(Ag + goff[q] + k0_, &lds[(b_) * 32768 + loff[q]]);      \
    _Pragma("unroll") for (int q = 0; q < 4; ++q)                    \
        gl16(Wg + goff[q] + k0_, &lds[(b_) * 32768 + 16384 + loff[q]]); \
  } while (0)

  // swizzled 16B slot for kstep ks (K=16): logical cb = ks*2 + (l>>5)
  int slot[4];
#pragma unroll
  for (int ks = 0; ks < 4; ++ks) slot[ks] = (((ks * 2 + (l >> 5)) ^ (l & 7)) * 8);

  // frag row bases
  int arow[4], brow[2];
#pragma unroll
  for (int fm = 0; fm < 4; ++fm) arow[fm] = (wr * 128 + fm * 32 + (l & 31)) * 64;
#pragma unroll
  for (int fn = 0; fn < 2; ++fn) brow[fn] = 16384 + (wc * 64 + fn * 32 + (l & 31)) * 64;

  float16v acc[4][2];
#pragma unroll
  for (int i = 0; i < 4; ++i)
#pragma unroll
    for (int j = 0; j < 2; ++j) acc[i][j] = (float16v)0.f;

  STAGE8(0, 0);
  STAGE8(1, 1);
  asm volatile("s_waitcnt vmcnt(8)" ::: "memory"); SB;
  __builtin_amdgcn_s_barrier(); SB;

#pragma unroll
  for (int kt = 0; kt < 8; ++kt) {
    const int b = kt & 1;
    const ushort* lb = &lds[b * 32768];
    short8 bf[2][2], af[4][2];
    // ---- phase A: ks 0,1 ----
#pragma unroll
    for (int fn = 0; fn < 2; ++fn)
#pragma unroll
      for (int ks = 0; ks < 2; ++ks)
        bf[fn][ks] = *(const short8*)&lb[brow[fn] + slot[ks]];
#pragma unroll
    for (int fm = 0; fm < 4; ++fm)
#pragma unroll
      for (int ks = 0; ks < 2; ++ks)
        af[fm][ks] = *(const short8*)&lb[arow[fm] + slot[ks]];
    asm volatile("s_waitcnt lgkmcnt(0)" ::: "memory"); SB;
    __builtin_amdgcn_s_setprio(1);
#pragma unroll
    for (int ks = 0; ks < 2; ++ks)
#pragma unroll
      for (int fm = 0; fm < 4; ++fm)
#pragma unroll
        for (int fn = 0; fn < 2; ++fn)
          acc[fm][fn] = __builtin_amdgcn_mfma_f32_32x32x16_bf16(
              af[fm][ks], bf[fn][ks], acc[fm][fn], 0, 0, 0);
    __builtin_amdgcn_s_setprio(0);
    // ---- phase B: ks 2,3 ----
#pragma unroll
    for (int fn = 0; fn < 2; ++fn)
#pragma unroll
      for (int ks = 0; ks < 2; ++ks)
        bf[fn][ks] = *(const short8*)&lb[brow[fn] + slot[2 + ks]];
#pragma unroll
    for (int fm = 0; fm < 4; ++fm)
#pragma unroll
      for (int ks = 0; ks < 2; ++ks)
        af[fm][ks] = *(const short8*)&lb[arow[fm] + slot[2 + ks]];
    asm volatile("s_waitcnt lgkmcnt(0)" ::: "memory"); SB;
    __builtin_amdgcn_s_barrier(); SB;   // all waves done reading buf b
    if (kt < 6) STAGE8(kt + 2, b);
    __builtin_amdgcn_s_setprio(1);
#pragma unroll
    for (int ks = 0; ks < 2; ++ks)
#pragma unroll
      for (int fm = 0; fm < 4; ++fm)
#pragma unroll
        for (int fn = 0; fn < 2; ++fn)
          acc[fm][fn] = __builtin_amdgcn_mfma_f32_32x32x16_bf16(
              af[fm][ks], bf[fn][ks], acc[fm][fn], 0, 0, 0);
    __builtin_amdgcn_s_setprio(0);
    if (kt < 7) {
      if (kt < 6) asm volatile("s_waitcnt vmcnt(8)" ::: "memory");
      else        asm volatile("s_waitcnt vmcnt(0)" ::: "memory");
      SB;
      __builtin_amdgcn_s_barrier(); SB;
    }
  }
#undef STAGE8

  SB; __builtin_amdgcn_s_barrier(); SB;

  // ---- epilogue: bias fold, partial BN stats, LDS-transpose bf16 store ----
  // C/D layout (32x32): col = l&31, row = (reg&3) + 8*(reg>>2) + 4*(l>>5)
  float bz[2];
#pragma unroll
  for (int fn = 0; fn < 2; ++fn)
    bz[fn] = BIAS ? bias2[bx * NC + n0 + wc * 64 + fn * 32 + (l & 31)] : 0.f;

#pragma unroll
  for (int fn = 0; fn < 2; ++fn) {
    float s = 0.f, q = 0.f;
#pragma unroll
    for (int fm = 0; fm < 4; ++fm)
#pragma unroll
      for (int reg = 0; reg < 16; ++reg) {
        float v = acc[fm][fn][reg] + bz[fn];
        acc[fm][fn][reg] = v;
        s += v;
        q = fmaf(v, v, q);
      }
    s += __shfl_xor(s, 32);
    q += __shfl_xor(q, 32);
    if (l < 32) {
      int mb = bx * 2 + wr;
      part[((size_t)g * 32 + mb) * NC + n0 + wc * 64 + fn * 32 + l] =
          make_float2(s, q);
    }
  }

  ushort* ep = &lds[w * 2432];  // 32 x 76 ushorts per wave (152B row stride)
  ushort* Hg = H + ((size_t)g * MF + m0 + wr * 128) * NC + n0 + wc * 64;
#pragma unroll
  for (int fm = 0; fm < 4; ++fm) {
#pragma unroll
    for (int fn = 0; fn < 2; ++fn)
#pragma unroll
      for (int reg = 0; reg < 16; ++reg) {
        int r32 = (reg & 3) + 8 * (reg >> 2) + 4 * (l >> 5);
        ep[r32 * 76 + fn * 32 + (l & 31)] = f2b(acc[fm][fn][reg]);
      }
#pragma unroll
    for (int it = 0; it < 4; ++it) {
      int u = it * 64 + l;
      int r = u >> 3, q = u & 7;
      short8 v = *(const short8*)&ep[r * 76 + q * 8];
      *(short8*)&Hg[(size_t)(fm * 32 + r) * NC + q * 8] = v;
    }
  }
}

// ---------------- stats finalize: (scale, shift) per (g,o) from 32 partials ------
__global__ __launch_bounds__(256) void k_stats2(
    const float2* __restrict__ part, const float* __restrict__ gam,
    const float* __restrict__ bet, float2* __restrict__ st) {
  int bi = blockIdx.x;
  int g = bi >> 1;
  int o = (bi & 1) * 256 + threadIdx.x;
  float s = 0.f, q = 0.f;
#pragma unroll
  for (int mb = 0; mb < 32; ++mb) {
    float2 v = part[((size_t)g * 32 + mb) * NC + o];
    s += v.x;
    q += v.y;
  }
  float mu = s * (1.f / 4096.f);
  float var = q * (1.f / 4096.f) - mu * mu;
  float sc = rsqrtf(var + EPS) * gam[o];
  st[g * NC + o] = make_float2(sc, bet[o] - mu * sc);
}

// ---------------- act: a1 = bf16(lrelu(h1*sc+sh)) --------------------------------
__global__ __launch_bounds__(256) void k_act(
    const ushort* __restrict__ h1, const float2* __restrict__ st,
    ushort* __restrict__ a1) {
  int g = blockIdx.z;
  size_t i0 = ((size_t)blockIdx.x * 256 + threadIdx.x) * 8;
  int o0 = (int)(i0 & 511);
  const ushort* src = h1 + (size_t)g * FRAME_ELEMS + i0;
  ushort* dst = a1 + (size_t)g * FRAME_ELEMS + i0;
  short8 v = *(const short8*)src;
  short8 r;
#pragma unroll
  for (int e = 0; e < 8; ++e) {
    float2 ss = st[g * NC + o0 + e];
    float x = fmaf(b2f((ushort)v[e]), ss.x, ss.y);
    r[e] = (short)f2b(lrelu(x));
  }
  *(short8*)dst = r;
}

// ---------------- conv3: 2x2 stride-2, inline bn+leaky, 16-lane channel split ----
__global__ __launch_bounds__(256) void k_conv3(
    const ushort* __restrict__ h2, const float2* __restrict__ st2,
    const float* __restrict__ w3, float* __restrict__ out, int f0) {
  int g = blockIdx.z;
  int b = blockIdx.x >> 2;
  int q = blockIdx.x & 3;
  int t = threadIdx.x;
  int oi = q * 16 + (t >> 4);
  int cs = t & 15;
  int y = oi >> 3, x = oi & 7;
  const ushort* base = h2 + ((size_t)g * MF + b * NHW) * NC;
  int m00 = (2 * y) * 16 + 2 * x;
  float acc = 0.f;
#pragma unroll
  for (int c8 = cs * 32; c8 < cs * 32 + 32; c8 += 8) {
    short8 v0 = *(const short8*)&base[(size_t)(m00 + 0) * NC + c8];
    short8 v1 = *(const short8*)&base[(size_t)(m00 + 1) * NC + c8];
    short8 v2 = *(const short8*)&base[(size_t)(m00 + 16) * NC + c8];
    short8 v3 = *(const short8*)&base[(size_t)(m00 + 17) * NC + c8];
#pragma unroll
    for (int e = 0; e < 8; ++e) {
      float2 ss = st2[g * NC + c8 + e];
      float4 wv = ((const float4*)w3)[c8 + e];
      acc = fmaf(lrelu(fmaf(b2f((ushort)v0[e]), ss.x, ss.y)), wv.x, acc);
      acc = fmaf(lrelu(fmaf(b2f((ushort)v1[e]), ss.x, ss.y)), wv.y, acc);
      acc = fmaf(lrelu(fmaf(b2f((ushort)v2[e]), ss.x, ss.y)), wv.z, acc);
      acc = fmaf(lrelu(fmaf(b2f((ushort)v3[e]), ss.x, ss.y)), wv.w, acc);
    }
  }
  acc += __shfl_xor(acc, 1);
  acc += __shfl_xor(acc, 2);
  acc += __shfl_xor(acc, 4);
  acc += __shfl_xor(acc, 8);
  if (cs == 0) out[((size_t)(f0 + g) * NBATCH + b) * 64 + oi] = acc;
}

extern "C" void kernel_launch(void* const* d_in, const int* in_sizes, int n_in,
                              void* d_out, int out_size, void* d_ws, size_t ws_size,
                              hipStream_t stream) {
  const float* cond = (const float*)d_in[0];
  const float* xbar = (const float*)d_in[1];
  const float* lin_w = (const float*)d_in[2];
  const float* lin_b = (const float*)d_in[3];
  const float* bnsg = (const float*)d_in[4];
  const float* bnsb = (const float*)d_in[5];
  const float* w1 = (const float*)d_in[6];
  const float* bn1g = (const float*)d_in[7];
  const float* bn1b = (const float*)d_in[8];
  const float* w2 = (const float*)d_in[9];
  const float* bn2g = (const float*)d_in[10];
  const float* bn2b = (const float*)d_in[11];
  const float* w3 = (const float*)d_in[12];
  float* out = (float*)d_out;

  char* p = (char*)d_ws;
  float* bias2 = (float*)p;   p += ((NBATCH * NC * 4 + 255) & ~255);
  float2* st1 = (float2*)p;   p += ((NF * NC * 8 + 255) & ~255);
  float2* st2 = (float2*)p;   p += ((NF * NC * 8 + 255) & ~255);
  float2* part = (float2*)p;  p += (((size_t)NF * 32 * NC * 8 + 255) & ~255);
  ushort* w1b = (ushort*)p;   p += ((NC * NC * 2 + 255) & ~255);
  ushort* w2b = (ushort*)p;   p += ((NC * NC * 2 + 255) & ~255);
  size_t used = (size_t)(p - (char*)d_ws);
  const size_t frame_bytes = FRAME_ELEMS * 2;  // 4.19 MB bf16
  size_t rem = ws_size > used ? ws_size - used : 0;
  int FB = (int)(rem / (3 * frame_bytes));
  if (FB < 1) FB = 1;
  if (FB > NF) FB = NF;
  ushort* bufA = (ushort*)p;                       // mot, then a1 (after gemm1)
  ushort* bufB = bufA + (size_t)FB * FRAME_ELEMS;  // h1
  ushort* bufC = bufB + (size_t)FB * FRAME_ELEMS;  // h2

  k_pre<<<1026, 256, 0, stream>>>(w1, w2, cond, lin_w, lin_b, bnsg, bnsb,
                                  w1b, w2b, bias2);

  for (int f0 = 0; f0 < NF; f0 += FB) {
    int nb = (NF - f0) < FB ? (NF - f0) : FB;
    int ngrp = (nb + 3) / 4;
    k_mot<<<dim3(32, NBATCH, ngrp), 256, 0, stream>>>(xbar, bufA, f0, nb);
    k_gemm8<0><<<dim3(16, 2, nb), 512, 0, stream>>>(bufA, w1b, nullptr, bufB, part);
    k_stats2<<<2 * nb, 256, 0, stream>>>(part, bn1g, bn1b, st1);
    k_act<<<dim3(1024, 1, nb), 256, 0, stream>>>(bufB, st1, bufA);
    k_gemm8<1><<<dim3(16, 2, nb), 512, 0, stream>>>(bufA, w2b, bias2, bufC, part);
    k_stats2<<<2 * nb, 256, 0, stream>>>(part, bn2g, bn2b, st2);
    k_conv3<<<dim3(NBATCH * 4, 1, nb), 256, 0, stream>>>(bufC, st2, w3, out, f0);
  }
}

// Round 18
// 254.848 us; speedup vs baseline: 1.0291x; 1.0291x over previous
//
#include <hip/hip_runtime.h>
#include <hip/hip_bf16.h>

#define EPS 1e-5f
#define SLOPE 0.2f

#define NF 16      // frames = T-1
#define NBATCH 16  // batch B
#define NC 512     // channels C (= GEMM N and K)
#define NHW 256    // H*W
#define ND 256     // cond dim D
#define K2 768     // C + D (conv2_w row stride)
#define MF 4096    // per-frame GEMM M = B*HW
#define FRAME_ELEMS ((size_t)MF * NC)   // 2,097,152

typedef __attribute__((ext_vector_type(8))) short short8;
typedef __attribute__((ext_vector_type(4))) float float4v;

__device__ __forceinline__ float lrelu(float v) { return v >= 0.f ? v : SLOPE * v; }
__device__ __forceinline__ float b2f(ushort u) { union { float f; uint i; } x; x.i = ((uint)u) << 16; return x.f; }
__device__ __forceinline__ ushort f2b(float f) {
  uint i = __float_as_uint(f);
  return (ushort)((i + 0x7FFFu + ((i >> 16) & 1u)) >> 16);
}
__device__ __forceinline__ void gl16(const void* g, void* l) {
  __builtin_amdgcn_global_load_lds(
      (const __attribute__((address_space(1))) unsigned int*)g,
      (__attribute__((address_space(3))) unsigned int*)l, 16, 0, 0);
}
#define SB __builtin_amdgcn_sched_barrier(0)

// ---------------- fused prep: weights->bf16 + sent(LDS) + bias2 -----------------
__global__ __launch_bounds__(256) void k_pre(
    const float* __restrict__ w1, const float* __restrict__ w2,
    const float* __restrict__ cond, const float* __restrict__ lin_w,
    const float* __restrict__ lin_b, const float* __restrict__ gam,
    const float* __restrict__ bet,
    ushort* __restrict__ w1b, ushort* __restrict__ w2b,
    float* __restrict__ bias2) {
  int bx = blockIdx.x, t = threadIdx.x;
  if (bx < 1024) {
    int i = bx * 256 + t;
    w1b[i] = f2b(w1[i]);
    int o = i >> 9, c = i & 511;
    w2b[i] = f2b(w2[(size_t)o * K2 + c]);
    return;
  }
  __shared__ float sl[NBATCH][ND];
  int d = t;
  {
    float acc[NBATCH];
    float bias = lin_b[d];
#pragma unroll
    for (int b = 0; b < NBATCH; ++b) acc[b] = bias;
    for (int k = 0; k < ND; ++k) {
      float w = lin_w[d * ND + k];
#pragma unroll
      for (int b = 0; b < NBATCH; ++b) acc[b] = fmaf(cond[b * ND + k], w, acc[b]);
    }
    float mu = 0.f;
#pragma unroll
    for (int b = 0; b < NBATCH; ++b) mu += acc[b];
    mu *= (1.f / NBATCH);
    float var = 0.f;
#pragma unroll
    for (int b = 0; b < NBATCH; ++b) { float x = acc[b] - mu; var = fmaf(x, x, var); }
    var *= (1.f / NBATCH);
    float sc = rsqrtf(var + EPS) * gam[d];
    float sh = bet[d] - mu * sc;
#pragma unroll
    for (int b = 0; b < NBATCH; ++b) sl[b][d] = lrelu(fmaf(acc[b], sc, sh));
  }
  __syncthreads();
  int o = (bx - 1024) * 256 + t;
  float acc2[NBATCH];
#pragma unroll
  for (int b = 0; b < NBATCH; ++b) acc2[b] = 0.f;
  for (int d2 = 0; d2 < ND; ++d2) {
    float wv = w2[(size_t)o * K2 + NC + d2];
#pragma unroll
    for (int b = 0; b < NBATCH; ++b) acc2[b] = fmaf(sl[b][d2], wv, acc2[b]);
  }
#pragma unroll
  for (int b = 0; b < NBATCH; ++b) bias2[b * NC + o] = acc2[b];
}

// ---------------- motions v5: micro-transpose + frame-group-4 register carry -----
// grid (32, NBATCH, ceil(nb/4)): each block does a (c0,hw0) 64x64 patch for up to
// 4 consecutive diffs, loading each interior frame ONCE (register carry) and
// prefetching frame fr+2 while frame fr's LDS/store phase runs.
__global__ __launch_bounds__(256) void k_mot(
    const float* __restrict__ xbar, ushort* __restrict__ mot, int f0, int nb) {
  __shared__ ushort T2[64][72];  // row = hw-in-tile; 128B data + 16B pad
  int t = threadIdx.x;
  int b = blockIdx.y;
  int hw0 = (blockIdx.x & 3) * 64;
  int c0 = (blockIdx.x >> 2) * 64;
  int fg = blockIdx.z * 4;
  int fe = fg + 4 < nb ? fg + 4 : nb;

  int c4 = t >> 4;   // c-quad 0..15
  int h16 = t & 15;  // hw-quad 0..15
  const size_t fstride = (size_t)NBATCH * NC * NHW;
  const float* base = xbar + ((size_t)(f0 + fg) * NBATCH + b) * (NC * NHW) +
                      (size_t)(c0 + c4 * 4) * NHW + hw0 + h16 * 4;

  float4 prev[4], cur[4], nxt[4];
#pragma unroll
  for (int r = 0; r < 4; ++r) prev[r] = *(const float4*)(base + (size_t)r * NHW);
#pragma unroll
  for (int r = 0; r < 4; ++r) cur[r] = *(const float4*)(base + fstride + (size_t)r * NHW);

  for (int fr = fg; fr < fe; ++fr) {
    if (fr + 1 < fe) {  // prefetch frame fr+2 during this frame's LDS/store phase
      const float* xn = base + (size_t)(fr - fg + 2) * fstride;
#pragma unroll
      for (int r = 0; r < 4; ++r) nxt[r] = *(const float4*)(xn + (size_t)r * NHW);
    }
#pragma unroll
    for (int i = 0; i < 4; ++i) {
      ushort4 pk = make_ushort4(
          f2b(((const float*)&cur[0])[i] - ((const float*)&prev[0])[i]),
          f2b(((const float*)&cur[1])[i] - ((const float*)&prev[1])[i]),
          f2b(((const float*)&cur[2])[i] - ((const float*)&prev[2])[i]),
          f2b(((const float*)&cur[3])[i] - ((const float*)&prev[3])[i]));
      *(ushort4*)&T2[h16 * 4 + i][c4 * 4] = pk;
    }
    __syncthreads();
    ushort* mp = mot + ((size_t)fr * MF + b * NHW + hw0) * NC + c0;
#pragma unroll
    for (int it = 0; it < 2; ++it) {
      int unit = it * 256 + t;
      int hw = unit >> 3, q = unit & 7;
      short8 v = *(const short8*)&T2[hw][q * 8];
      *(short8*)&mp[(size_t)hw * NC + q * 8] = v;
    }
    __syncthreads();
#pragma unroll
    for (int r = 0; r < 4; ++r) { prev[r] = cur[r]; cur[r] = nxt[r]; }
  }
}

// ---------------- 256x256 8-wave MFMA GEMM, counted-vmcnt dbuf pipeline ----------
template <int BIAS>
__global__ __launch_bounds__(512, 2) void k_gemm8(
    const ushort* __restrict__ A, const ushort* __restrict__ W,
    const float* __restrict__ bias2, ushort* __restrict__ H,
    float2* __restrict__ part) {
  __shared__ ushort lds[65536];  // [buf][A:16384|B:16384]
  const int t = threadIdx.x, w = t >> 6, l = t & 63;
  const int g = blockIdx.z, bx = blockIdx.x, ny = blockIdx.y;
  const int m0 = bx * 256, n0 = ny * 256;
  const int wr = w >> 2, wc = w & 3;

  const ushort* Ag = A + (size_t)g * FRAME_ELEMS + (size_t)m0 * NC;
  const ushort* Wg = W + (size_t)n0 * NC;

  size_t goff[4];
  int loff[4];
#pragma unroll
  for (int q = 0; q < 4; ++q) {
    int u = w * 256 + q * 64 + l;
    int row = u >> 3, cb = (u & 7) ^ (row & 7);
    goff[q] = (size_t)row * NC + cb * 8;
    loff[q] = u * 8;
  }

#define STAGE8(t_, b_)                                               \
  do {                                                               \
    const int k0_ = (t_) * 64;                                       \
    _Pragma("unroll") for (int q = 0; q < 4; ++q)                    \
        gl16(Ag + goff[q] + k0_, &lds[(b_) * 32768 + loff[q]]);      \
    _Pragma("unroll") for (int q = 0; q < 4; ++q)                    \
        gl16(Wg + goff[q] + k0_, &lds[(b_) * 32768 + 16384 + loff[q]]); \
  } while (0)

  int slot[2];
#pragma unroll
  for (int kk = 0; kk < 2; ++kk) slot[kk] = (((kk * 4 + (l >> 4)) ^ (l & 7)) * 8);

  float4v acc[8][4];
#pragma unroll
  for (int i = 0; i < 8; ++i)
#pragma unroll
    for (int j = 0; j < 4; ++j) acc[i][j] = (float4v)0.f;

  STAGE8(0, 0);
  STAGE8(1, 1);
  asm volatile("s_waitcnt vmcnt(8)" ::: "memory"); SB;
  __builtin_amdgcn_s_barrier(); SB;

#pragma unroll
  for (int kt = 0; kt < 8; ++kt) {
    const int b = kt & 1;
    const ushort* la = &lds[b * 32768];
    const ushort* lb = la + 16384;
    short8 bf[4][2], af[4][2];
#pragma unroll
    for (int fn = 0; fn < 4; ++fn) {
      int r = wc * 64 + fn * 16 + (l & 15);
#pragma unroll
      for (int kk = 0; kk < 2; ++kk)
        bf[fn][kk] = *(const short8*)&lb[r * 64 + slot[kk]];
    }
#pragma unroll
    for (int fm = 0; fm < 4; ++fm) {
      int r = wr * 128 + fm * 16 + (l & 15);
#pragma unroll
      for (int kk = 0; kk < 2; ++kk)
        af[fm][kk] = *(const short8*)&la[r * 64 + slot[kk]];
    }
    asm volatile("s_waitcnt lgkmcnt(0)" ::: "memory"); SB;
    __builtin_amdgcn_s_setprio(1);
#pragma unroll
    for (int kk = 0; kk < 2; ++kk)
#pragma unroll
      for (int fm = 0; fm < 4; ++fm)
#pragma unroll
        for (int fn = 0; fn < 4; ++fn)
          acc[fm][fn] = __builtin_amdgcn_mfma_f32_16x16x32_bf16(
              af[fm][kk], bf[fn][kk], acc[fm][fn], 0, 0, 0);
    __builtin_amdgcn_s_setprio(0);
#pragma unroll
    for (int fm = 0; fm < 4; ++fm) {
      int r = wr * 128 + 64 + fm * 16 + (l & 15);
#pragma unroll
      for (int kk = 0; kk < 2; ++kk)
        af[fm][kk] = *(const short8*)&la[r * 64 + slot[kk]];
    }
    asm volatile("s_waitcnt lgkmcnt(0)" ::: "memory"); SB;
    __builtin_amdgcn_s_barrier(); SB;   // all waves done reading buf b
    if (kt < 6) STAGE8(kt + 2, b);
    __builtin_amdgcn_s_setprio(1);
#pragma unroll
    for (int kk = 0; kk < 2; ++kk)
#pragma unroll
      for (int fm = 0; fm < 4; ++fm)
#pragma unroll
        for (int fn = 0; fn < 4; ++fn)
          acc[fm + 4][fn] = __builtin_amdgcn_mfma_f32_16x16x32_bf16(
              af[fm][kk], bf[fn][kk], acc[fm + 4][fn], 0, 0, 0);
    __builtin_amdgcn_s_setprio(0);
    if (kt < 7) {
      if (kt < 6) asm volatile("s_waitcnt vmcnt(8)" ::: "memory");
      else        asm volatile("s_waitcnt vmcnt(0)" ::: "memory");
      SB;
      __builtin_amdgcn_s_barrier(); SB;
    }
  }
#undef STAGE8

  SB; __builtin_amdgcn_s_barrier(); SB;

  float bz[4];
#pragma unroll
  for (int fn = 0; fn < 4; ++fn)
    bz[fn] = BIAS ? bias2[bx * NC + n0 + wc * 64 + fn * 16 + (l & 15)] : 0.f;

  float sv[4], qv[4];
#pragma unroll
  for (int fn = 0; fn < 4; ++fn) {
    float s = 0.f, q = 0.f;
#pragma unroll
    for (int fm = 0; fm < 8; ++fm)
#pragma unroll
      for (int j = 0; j < 4; ++j) {
        float v = acc[fm][fn][j] + bz[fn];
        acc[fm][fn][j] = v;
        s += v;
        q = fmaf(v, v, q);
      }
    s += __shfl_xor(s, 16); s += __shfl_xor(s, 32);
    q += __shfl_xor(q, 16); q += __shfl_xor(q, 32);
    sv[fn] = s; qv[fn] = q;
  }
  if (l < 16) {
    int mb = bx * 2 + wr;
    float2* pp = part + ((size_t)g * 32 + mb) * NC + n0 + wc * 64 + l;
#pragma unroll
    for (int fn = 0; fn < 4; ++fn) pp[fn * 16] = make_float2(sv[fn], qv[fn]);
  }

  ushort* ep = &lds[w * 1088];  // 16 x 68 per wave
  ushort* Hg = H + ((size_t)g * MF + m0 + wr * 128) * NC + n0 + wc * 64;
#pragma unroll
  for (int fm = 0; fm < 8; ++fm) {
#pragma unroll
    for (int fn = 0; fn < 4; ++fn)
#pragma unroll
      for (int j = 0; j < 4; ++j)
        ep[((l >> 4) * 4 + j) * 68 + fn * 16 + (l & 15)] = f2b(acc[fm][fn][j]);
#pragma unroll
    for (int h = 0; h < 2; ++h) {
      int r = h * 8 + (l >> 3), sl = l & 7;
      short8 v = *(const short8*)&ep[r * 68 + sl * 8];
      *(short8*)&Hg[(size_t)(fm * 16 + r) * NC + sl * 8] = v;
    }
  }
}

// ---------------- stats finalize: (scale, shift) per (g,o) from 32 partials ------
__global__ __launch_bounds__(256) void k_stats2(
    const float2* __restrict__ part, const float* __restrict__ gam,
    const float* __restrict__ bet, float2* __restrict__ st) {
  int bi = blockIdx.x;
  int g = bi >> 1;
  int o = (bi & 1) * 256 + threadIdx.x;
  float s = 0.f, q = 0.f;
#pragma unroll
  for (int mb = 0; mb < 32; ++mb) {
    float2 v = part[((size_t)g * 32 + mb) * NC + o];
    s += v.x;
    q += v.y;
  }
  float mu = s * (1.f / 4096.f);
  float var = q * (1.f / 4096.f) - mu * mu;
  float sc = rsqrtf(var + EPS) * gam[o];
  st[g * NC + o] = make_float2(sc, bet[o] - mu * sc);
}

// ---------------- act: a1 = bf16(lrelu(h1*sc+sh)) --------------------------------
__global__ __launch_bounds__(256) void k_act(
    const ushort* __restrict__ h1, const float2* __restrict__ st,
    ushort* __restrict__ a1) {
  int g = blockIdx.z;
  size_t i0 = ((size_t)blockIdx.x * 256 + threadIdx.x) * 8;
  int o0 = (int)(i0 & 511);
  const ushort* src = h1 + (size_t)g * FRAME_ELEMS + i0;
  ushort* dst = a1 + (size_t)g * FRAME_ELEMS + i0;
  short8 v = *(const short8*)src;
  short8 r;
#pragma unroll
  for (int e = 0; e < 8; ++e) {
    float2 ss = st[g * NC + o0 + e];
    float x = fmaf(b2f((ushort)v[e]), ss.x, ss.y);
    r[e] = (short)f2b(lrelu(x));
  }
  *(short8*)dst = r;
}

// ---------------- conv3: 2x2 stride-2, inline bn+leaky, 16-lane channel split ----
__global__ __launch_bounds__(256) void k_conv3(
    const ushort* __restrict__ h2, const float2* __restrict__ st2,
    const float* __restrict__ w3, float* __restrict__ out, int f0) {
  int g = blockIdx.z;
  int b = blockIdx.x >> 2;
  int q = blockIdx.x & 3;
  int t = threadIdx.x;
  int oi = q * 16 + (t >> 4);
  int cs = t & 15;
  int y = oi >> 3, x = oi & 7;
  const ushort* base = h2 + ((size_t)g * MF + b * NHW) * NC;
  int m00 = (2 * y) * 16 + 2 * x;
  float acc = 0.f;
#pragma unroll
  for (int c8 = cs * 32; c8 < cs * 32 + 32; c8 += 8) {
    short8 v0 = *(const short8*)&base[(size_t)(m00 + 0) * NC + c8];
    short8 v1 = *(const short8*)&base[(size_t)(m00 + 1) * NC + c8];
    short8 v2 = *(const short8*)&base[(size_t)(m00 + 16) * NC + c8];
    short8 v3 = *(const short8*)&base[(size_t)(m00 + 17) * NC + c8];
#pragma unroll
    for (int e = 0; e < 8; ++e) {
      float2 ss = st2[g * NC + c8 + e];
      float4 wv = ((const float4*)w3)[c8 + e];
      acc = fmaf(lrelu(fmaf(b2f((ushort)v0[e]), ss.x, ss.y)), wv.x, acc);
      acc = fmaf(lrelu(fmaf(b2f((ushort)v1[e]), ss.x, ss.y)), wv.y, acc);
      acc = fmaf(lrelu(fmaf(b2f((ushort)v2[e]), ss.x, ss.y)), wv.z, acc);
      acc = fmaf(lrelu(fmaf(b2f((ushort)v3[e]), ss.x, ss.y)), wv.w, acc);
    }
  }
  acc += __shfl_xor(acc, 1);
  acc += __shfl_xor(acc, 2);
  acc += __shfl_xor(acc, 4);
  acc += __shfl_xor(acc, 8);
  if (cs == 0) out[((size_t)(f0 + g) * NBATCH + b) * 64 + oi] = acc;
}

extern "C" void kernel_launch(void* const* d_in, const int* in_sizes, int n_in,
                              void* d_out, int out_size, void* d_ws, size_t ws_size,
                              hipStream_t stream) {
  const float* cond = (const float*)d_in[0];
  const float* xbar = (const float*)d_in[1];
  const float* lin_w = (const float*)d_in[2];
  const float* lin_b = (const float*)d_in[3];
  const float* bnsg = (const float*)d_in[4];
  const float* bnsb = (const float*)d_in[5];
  const float* w1 = (const float*)d_in[6];
  const float* bn1g = (const float*)d_in[7];
  const float* bn1b = (const float*)d_in[8];
  const float* w2 = (const float*)d_in[9];
  const float* bn2g = (const float*)d_in[10];
  const float* bn2b = (const float*)d_in[11];
  const float* w3 = (const float*)d_in[12];
  float* out = (float*)d_out;

  char* p = (char*)d_ws;
  float* bias2 = (float*)p;   p += ((NBATCH * NC * 4 + 255) & ~255);
  float2* st1 = (float2*)p;   p += ((NF * NC * 8 + 255) & ~255);
  float2* st2 = (float2*)p;   p += ((NF * NC * 8 + 255) & ~255);
  float2* part = (float2*)p;  p += (((size_t)NF * 32 * NC * 8 + 255) & ~255);
  ushort* w1b = (ushort*)p;   p += ((NC * NC * 2 + 255) & ~255);
  ushort* w2b = (ushort*)p;   p += ((NC * NC * 2 + 255) & ~255);
  size_t used = (size_t)(p - (char*)d_ws);
  const size_t frame_bytes = FRAME_ELEMS * 2;  // 4.19 MB bf16
  size_t rem = ws_size > used ? ws_size - used : 0;
  int FB = (int)(rem / (3 * frame_bytes));
  if (FB < 1) FB = 1;
  if (FB > NF) FB = NF;
  ushort* bufA = (ushort*)p;                       // mot, then a1 (after gemm1)
  ushort* bufB = bufA + (size_t)FB * FRAME_ELEMS;  // h1
  ushort* bufC = bufB + (size_t)FB * FRAME_ELEMS;  // h2

  k_pre<<<1026, 256, 0, stream>>>(w1, w2, cond, lin_w, lin_b, bnsg, bnsb,
                                  w1b, w2b, bias2);

  for (int f0 = 0; f0 < NF; f0 += FB) {
    int nb = (NF - f0) < FB ? (NF - f0) : FB;
    int ngrp = (nb + 3) / 4;
    k_mot<<<dim3(32, NBATCH, ngrp), 256, 0, stream>>>(xbar, bufA, f0, nb);
    k_gemm8<0><<<dim3(16, 2, nb), 512, 0, stream>>>(bufA, w1b, nullptr, bufB, part);
    k_stats2<<<2 * nb, 256, 0, stream>>>(part, bn1g, bn1b, st1);
    k_act<<<dim3(1024, 1, nb), 256, 0, stream>>>(bufB, st1, bufA);
    k_gemm8<1><<<dim3(16, 2, nb), 512, 0, stream>>>(bufA, w2b, bias2, bufC, part);
    k_stats2<<<2 * nb, 256, 0, stream>>>(part, bn2g, bn2b, st2);
    k_conv3<<<dim3(NBATCH * 4, 1, nb), 256, 0, stream>>>(bufC, st2, w3, out, f0);
  }
}